// Round 1
// baseline (205.088 us; speedup 1.0000x reference)
//
#include <hip/hip_runtime.h>
#include <math.h>

#define BATCH 8192
#define SENTS 50
#define ED    256
#define NENT  20
#define BB    16

// log2(200)/256
#define RATE_K 0.0298588132413075f

// ---------------------------------------------------------------------------
// Kernel 0: precompute pos[s][e] = sin(s * 200^(-e/256)) into ws table
// ---------------------------------------------------------------------------
__global__ __launch_bounds__(256) void pos_kernel(float* __restrict__ pos_tab) {
    int s = blockIdx.x;
    int e = threadIdx.x;
    float rate = exp2f(-(float)e * RATE_K);
    pos_tab[s * ED + e] = sinf((float)s * rate);
}

// ---------------------------------------------------------------------------
// Kernel 1: per-batch streaming: x = sents+pos (LDS), logits, softmax,
// attn_hidden h, ent_sum*w = m. Writes h,m to workspace.
// ---------------------------------------------------------------------------
__global__ __launch_bounds__(256) void main_kernel(
    const float* __restrict__ sents, const float* __restrict__ entities,
    const float* __restrict__ dense_w, const float* __restrict__ pos_tab,
    float* __restrict__ h_out, float* __restrict__ m_out)
{
    __shared__ __align__(16) float xs[SENTS][ED + 4];   // pad: 260 floats/row (16B-aligned stride)
    __shared__ float logit_s[64];
    __shared__ float coef[64];

    int t    = threadIdx.x;
    int b    = blockIdx.x;
    int lane = t & 63;
    int w    = t >> 6;

    // ---- load x = sents[b] + pos into LDS (float4, coalesced) ----
    const float4* s4 = (const float4*)(sents + (size_t)b * SENTS * ED);
    const float4* p4 = (const float4*)pos_tab;
    int c4 = t & 63;   // column group 0..63
    int sr = t >> 6;   // row residue 0..3
    for (int s = sr; s < SENTS; s += 4) {
        float4 v = s4[s * 64 + c4];
        float4 p = p4[s * 64 + c4];
        v.x += p.x; v.y += p.y; v.z += p.z; v.w += p.w;
        *(float4*)&xs[s][c4 * 4] = v;
    }
    __syncthreads();

    // ---- logits[s] = x[s] . x[49]  (wave w handles s = w, w+4, ...) ----
    float4 q = *(const float4*)&xs[SENTS - 1][lane * 4];
    for (int s = w; s < SENTS; s += 4) {
        float4 v = *(const float4*)&xs[s][lane * 4];
        float p = v.x * q.x + v.y * q.y + v.z * q.z + v.w * q.w;
        p += __shfl_down(p, 32);
        p += __shfl_down(p, 16);
        p += __shfl_down(p, 8);
        p += __shfl_down(p, 4);
        p += __shfl_down(p, 2);
        p += __shfl_down(p, 1);
        if (lane == 0) logit_s[s] = p;
    }
    __syncthreads();

    // ---- softmax over 50 logits (wave 0) ----
    if (w == 0) {
        float l = (lane < SENTS) ? logit_s[lane] : -INFINITY;
        float mx = l;
        for (int off = 32; off >= 1; off >>= 1) mx = fmaxf(mx, __shfl_xor(mx, off));
        float ex = (lane < SENTS) ? expf(l - mx) : 0.f;
        float sm = ex;
        for (int off = 32; off >= 1; off >>= 1) sm += __shfl_xor(sm, off);
        if (lane < SENTS) coef[lane] = ex / sm;
    }
    __syncthreads();

    // ---- attn_hidden[e=t] = sum_s coef[s]*x[s][t] ----
    float h = 0.f;
    #pragma unroll
    for (int s = 0; s < SENTS; ++s) h += coef[s] * xs[s][t];

    // ---- ent_sum[e=t] = sum_n entities[b][n][t];  m = ent_sum * w[t] ----
    const float* ent = entities + (size_t)b * NENT * ED;
    float es = 0.f;
    #pragma unroll
    for (int n = 0; n < NENT; ++n) es += ent[n * ED + t];
    float m = es * dense_w[t];

    h_out[(size_t)b * ED + t] = h;
    m_out[(size_t)b * ED + t] = m;
}

// ---------------------------------------------------------------------------
// Kernel 2: out[b] = sigmoid( sum_e (sum_e' h[e'] A[e',e]) * m[e] + bias )
// BB batches per block; coalesced column reads of A (L2-resident).
// ---------------------------------------------------------------------------
__global__ __launch_bounds__(256) void bilinear_kernel(
    const float* __restrict__ hws, const float* __restrict__ mws,
    const float* __restrict__ A, const float* __restrict__ dense_b,
    float* __restrict__ out)
{
    __shared__ __align__(16) float hl[BB][ED];
    __shared__ float ml[BB][ED];
    __shared__ float part[BB][ED];

    int t  = threadIdx.x;
    int b0 = blockIdx.x * BB;

    for (int i = 0; i < BB; ++i) {
        hl[i][t] = hws[(size_t)(b0 + i) * ED + t];
        ml[i][t] = mws[(size_t)(b0 + i) * ED + t];
    }
    __syncthreads();

    float acc[BB];
    #pragma unroll
    for (int i = 0; i < BB; ++i) acc[i] = 0.f;

    for (int ep = 0; ep < ED; ep += 4) {
        float a0 = A[(ep + 0) * ED + t];
        float a1 = A[(ep + 1) * ED + t];
        float a2 = A[(ep + 2) * ED + t];
        float a3 = A[(ep + 3) * ED + t];
        #pragma unroll
        for (int i = 0; i < BB; ++i) {
            float4 hv = *(const float4*)&hl[i][ep];
            acc[i] += hv.x * a0 + hv.y * a1 + hv.z * a2 + hv.w * a3;
        }
    }

    #pragma unroll
    for (int i = 0; i < BB; ++i) part[i][t] = acc[i] * ml[i][t];
    __syncthreads();

    int lane = t & 63, w = t >> 6;
    float bias = dense_b[0];
    for (int i = w; i < BB; i += 4) {
        float v = part[i][lane] + part[i][lane + 64] + part[i][lane + 128] + part[i][lane + 192];
        for (int off = 32; off >= 1; off >>= 1) v += __shfl_xor(v, off);
        if (lane == 0) out[b0 + i] = 1.f / (1.f + expf(-(v + bias)));
    }
}

// ---------------------------------------------------------------------------
// Fallback: fully fused, no workspace (in case ws_size is tiny)
// ---------------------------------------------------------------------------
__global__ __launch_bounds__(256) void fused_kernel(
    const float* __restrict__ sents, const float* __restrict__ entities,
    const float* __restrict__ A, const float* __restrict__ dense_w,
    const float* __restrict__ dense_b, float* __restrict__ out)
{
    __shared__ __align__(16) float xs[SENTS][ED + 4];
    __shared__ float logit_s[64];
    __shared__ float coef[64];
    __shared__ __align__(16) float harr[ED];
    __shared__ float marr[ED];
    __shared__ float red[4];

    int t    = threadIdx.x;
    int b    = blockIdx.x;
    int lane = t & 63;
    int w    = t >> 6;

    float rate = exp2f(-(float)t * RATE_K);
    const float* sp = sents + (size_t)b * SENTS * ED;
    for (int s = 0; s < SENTS; ++s)
        xs[s][t] = sp[s * ED + t] + sinf((float)s * rate);
    __syncthreads();

    float4 q = *(const float4*)&xs[SENTS - 1][lane * 4];
    for (int s = w; s < SENTS; s += 4) {
        float4 v = *(const float4*)&xs[s][lane * 4];
        float p = v.x * q.x + v.y * q.y + v.z * q.z + v.w * q.w;
        p += __shfl_down(p, 32);
        p += __shfl_down(p, 16);
        p += __shfl_down(p, 8);
        p += __shfl_down(p, 4);
        p += __shfl_down(p, 2);
        p += __shfl_down(p, 1);
        if (lane == 0) logit_s[s] = p;
    }
    __syncthreads();

    if (w == 0) {
        float l = (lane < SENTS) ? logit_s[lane] : -INFINITY;
        float mx = l;
        for (int off = 32; off >= 1; off >>= 1) mx = fmaxf(mx, __shfl_xor(mx, off));
        float ex = (lane < SENTS) ? expf(l - mx) : 0.f;
        float sm = ex;
        for (int off = 32; off >= 1; off >>= 1) sm += __shfl_xor(sm, off);
        if (lane < SENTS) coef[lane] = ex / sm;
    }
    __syncthreads();

    float h = 0.f;
    #pragma unroll
    for (int s = 0; s < SENTS; ++s) h += coef[s] * xs[s][t];

    const float* ent = entities + (size_t)b * NENT * ED;
    float es = 0.f;
    #pragma unroll
    for (int n = 0; n < NENT; ++n) es += ent[n * ED + t];
    float m = es * dense_w[t];

    harr[t] = h;
    marr[t] = m;
    __syncthreads();

    float acc = 0.f;
    for (int ep = 0; ep < ED; ep += 4) {
        float4 hv = *(const float4*)&harr[ep];
        acc += hv.x * A[(ep + 0) * ED + t];
        acc += hv.y * A[(ep + 1) * ED + t];
        acc += hv.z * A[(ep + 2) * ED + t];
        acc += hv.w * A[(ep + 3) * ED + t];
    }
    float val = acc * marr[t];
    val += __shfl_down(val, 32);
    val += __shfl_down(val, 16);
    val += __shfl_down(val, 8);
    val += __shfl_down(val, 4);
    val += __shfl_down(val, 2);
    val += __shfl_down(val, 1);
    if (lane == 0) red[w] = val;
    __syncthreads();
    if (t == 0) {
        float tot = red[0] + red[1] + red[2] + red[3];
        out[b] = 1.f / (1.f + expf(-(tot + dense_b[0])));
    }
}

extern "C" void kernel_launch(void* const* d_in, const int* in_sizes, int n_in,
                              void* d_out, int out_size, void* d_ws, size_t ws_size,
                              hipStream_t stream) {
    const float* sents    = (const float*)d_in[0];
    const float* entities = (const float*)d_in[1];
    const float* A        = (const float*)d_in[2];
    const float* dense_w  = (const float*)d_in[3];
    const float* dense_b  = (const float*)d_in[4];
    float* out = (float*)d_out;

    size_t pos_bytes = (size_t)SENTS * ED * sizeof(float);          // 51200
    size_t hm_bytes  = (size_t)BATCH * ED * sizeof(float);          // 8 MB each
    size_t need = pos_bytes + 2 * hm_bytes;

    if (ws_size >= need) {
        float* pos_tab = (float*)d_ws;
        float* hws = (float*)((char*)d_ws + pos_bytes);
        float* mws = (float*)((char*)d_ws + pos_bytes + hm_bytes);
        pos_kernel<<<SENTS, ED, 0, stream>>>(pos_tab);
        main_kernel<<<BATCH, 256, 0, stream>>>(sents, entities, dense_w, pos_tab, hws, mws);
        bilinear_kernel<<<BATCH / BB, 256, 0, stream>>>(hws, mws, A, dense_b, out);
    } else {
        fused_kernel<<<BATCH, 256, 0, stream>>>(sents, entities, A, dense_w, dense_b, out);
    }
}